// Round 3
// baseline (50.350 us; speedup 1.0000x reference)
//
#include <hip/hip_runtime.h>

using bf16x8 = __attribute__((ext_vector_type(8))) short;
using f32x4  = __attribute__((ext_vector_type(4))) float;

constexpr int N_ = 512;
constexpr int C_ = 32;

// f32 -> bf16 (RNE)
__device__ __forceinline__ short f2bf(float x) {
    unsigned u = __builtin_bit_cast(unsigned, x);
    unsigned r = (u + 0x7FFFu + ((u >> 16) & 1u)) >> 16;
    return (short)r;
}

// Orientation: H^T = mfma(A=W1, B=rbf^T); R^T = mfma(A=W2, B=H).
// C-layout: lane(lg,lr) holds col i=lr (edge), rows m=4*lg+r (+16 for hi tile).
__global__ __launch_bounds__(256, 4)
void filter_mfma2(const float* __restrict__ tensor,  // [B,N,C,3]
                  const float* __restrict__ rbf,     // [B,N,N,32]
                  const float* __restrict__ rij,     // [B,N,N,3]
                  const float* __restrict__ W1,
                  const float* __restrict__ b1,
                  const float* __restrict__ W2,
                  const float* __restrict__ b2,
                  float* __restrict__ out)           // [B,N,C]
{
    const int bid  = blockIdx.x;
    const int bn   = bid >> 1;          // which (b,n)
    const int half = bid & 1;           // k-split half: edges [half*256, half*256+256)
    const int b    = bn >> 9;
    const int tid  = threadIdx.x;
    const int lane = tid & 63;
    const int w    = tid >> 6;
    const int lr   = lane & 15;
    const int lg   = lane >> 4;

    __shared__ float Hs[4][32][18];   // per-wave private, stride 18 -> <=2-way banks
    __shared__ float red[4][4][8];

    // Weight A-fragments: lane holds row m=lr(+16), k=8*lg+e
    bf16x8 W1a[2], W2a[2];
    #pragma unroll
    for (int t = 0; t < 2; ++t) {
        const float* p1 = W1 + (lr + 16 * t) * 32 + 8 * lg;
        const float* p2 = W2 + (lr + 16 * t) * 32 + 8 * lg;
        #pragma unroll
        for (int e = 0; e < 8; ++e) { W1a[t][e] = f2bf(p1[e]); W2a[t][e] = f2bf(p2[e]); }
    }
    // Biases for the C-layout rows this lane owns: m = 4*lg+r (+16)
    float b1lo[4], b1hi[4], b2lo[4], b2hi[4];
    #pragma unroll
    for (int r = 0; r < 4; ++r) {
        b1lo[r] = b1[4 * lg + r];      b1hi[r] = b1[16 + 4 * lg + r];
        b2lo[r] = b2[4 * lg + r];      b2hi[r] = b2[16 + 4 * lg + r];
    }

    const float* rbf_bn = rbf + (size_t)bn * (N_ * 32);
    const float* rij_bn = rij + (size_t)bn * (N_ * 3);
    const float* ten_b  = tensor + (size_t)b * (N_ * C_ * 3);

    float acc[8];
    #pragma unroll
    for (int c = 0; c < 8; ++c) acc[c] = 0.f;

    for (int j = 0; j < 4; ++j) {
        const int e0 = half * 256 + (w * 4 + j) * 16;
        const int k  = e0 + lr;              // this lane's edge (epilogue)

        // rbf B-fragment: lane holds col i=lr, k=8*lg+e
        const float* ap = rbf_bn + (size_t)(e0 + lr) * 32 + 8 * lg;
        const f32x4 a0 = *(const f32x4*)ap;
        const f32x4 a1 = *(const f32x4*)(ap + 4);
        bf16x8 X;
        #pragma unroll
        for (int e = 0; e < 4; ++e) { X[e] = f2bf(a0[e]); X[4 + e] = f2bf(a1[e]); }

        // Epilogue operands issued early (hide under MFMAs / LDS round-trip)
        const float rx = rij_bn[k * 3 + 0];
        const float ry = rij_bn[k * 3 + 1];
        const float rz = rij_bn[k * 3 + 2];
        const float* tp = ten_b + ((size_t)k * C_ + 4 * lg) * 3;   // 16B-aligned
        const f32x4 f0 = ((const f32x4*)tp)[0];
        const f32x4 f1 = ((const f32x4*)tp)[1];
        const f32x4 f2v = ((const f32x4*)tp)[2];
        const float* tq = tp + 48;                                  // +16 channels
        const f32x4 g0 = ((const f32x4*)tq)[0];
        const f32x4 g1 = ((const f32x4*)tq)[1];
        const f32x4 g2 = ((const f32x4*)tq)[2];

        // Layer 1
        f32x4 h0 = {0,0,0,0}, h1 = {0,0,0,0};
        h0 = __builtin_amdgcn_mfma_f32_16x16x32_bf16(W1a[0], X, h0, 0, 0, 0);
        h1 = __builtin_amdgcn_mfma_f32_16x16x32_bf16(W1a[1], X, h1, 0, 0, 0);
        #pragma unroll
        for (int r = 0; r < 4; ++r) {
            Hs[w][4 * lg + r][lr]      = fmaxf(h0[r] + b1lo[r], 0.f);
            Hs[w][16 + 4 * lg + r][lr] = fmaxf(h1[r] + b1hi[r], 0.f);
        }
        asm volatile("s_waitcnt lgkmcnt(0)" ::: "memory");
        __builtin_amdgcn_sched_barrier(0);

        // H B-fragment: lane holds col i=lr, l=8*lg+e
        bf16x8 Hf;
        #pragma unroll
        for (int e = 0; e < 8; ++e) Hf[e] = f2bf(Hs[w][8 * lg + e][lr]);

        // Layer 2
        f32x4 r0 = {0,0,0,0}, r1 = {0,0,0,0};
        r0 = __builtin_amdgcn_mfma_f32_16x16x32_bf16(W2a[0], Hf, r0, 0, 0, 0);
        r1 = __builtin_amdgcn_mfma_f32_16x16x32_bf16(W2a[1], Hf, r1, 0, 0, 0);

        // Epilogue: one edge per lane, 8 channels
        const float r2 = rx * rx + ry * ry + rz * rz;
        const float inv = rsqrtf(fmaxf(r2, 1e-8f));
        const float vm = (r2 >= 1e-16f) ? 1.f : 0.f;   // |rij| >= 1e-8
        const float s0 = (rx * f0[0] + ry * f0[1] + rz * f0[2]) * inv;
        const float s1 = (rx * f0[3] + ry * f1[0] + rz * f1[1]) * inv;
        const float s2 = (rx * f1[2] + ry * f1[3] + rz * f2v[0]) * inv;
        const float s3 = (rx * f2v[1] + ry * f2v[2] + rz * f2v[3]) * inv;
        const float t0 = (rx * g0[0] + ry * g0[1] + rz * g0[2]) * inv;
        const float t1 = (rx * g0[3] + ry * g1[0] + rz * g1[1]) * inv;
        const float t2 = (rx * g1[2] + ry * g1[3] + rz * g2[0]) * inv;
        const float t3 = (rx * g2[1] + ry * g2[2] + rz * g2[3]) * inv;
        acc[0] += vm * (r0[0] + b2lo[0]) * s0;
        acc[1] += vm * (r0[1] + b2lo[1]) * s1;
        acc[2] += vm * (r0[2] + b2lo[2]) * s2;
        acc[3] += vm * (r0[3] + b2lo[3]) * s3;
        acc[4] += vm * (r1[0] + b2hi[0]) * t0;
        acc[5] += vm * (r1[1] + b2hi[1]) * t1;
        acc[6] += vm * (r1[2] + b2hi[2]) * t2;
        acc[7] += vm * (r1[3] + b2hi[3]) * t3;
    }

    // Sum over the 16 edges held across lr within each 16-lane group.
    #pragma unroll
    for (int c = 0; c < 8; ++c) {
        #pragma unroll
        for (int msk = 1; msk < 16; msk <<= 1)
            acc[c] += __shfl_xor(acc[c], msk, 64);
    }
    if (lr == 0) {
        #pragma unroll
        for (int c = 0; c < 8; ++c) red[w][lg][c] = acc[c];
    }
    __syncthreads();
    if (tid < 32) {
        const int m = tid, hi = m >> 4, lgq = (m & 15) >> 2, r = m & 3;
        float t = 0.f;
        #pragma unroll
        for (int ww = 0; ww < 4; ++ww) t += red[ww][lgq][hi * 4 + r];
        atomicAdd(out + bn * C_ + m, t);   // exactly 2 adds/element -> deterministic
    }
}

extern "C" void kernel_launch(void* const* d_in, const int* in_sizes, int n_in,
                              void* d_out, int out_size, void* d_ws, size_t ws_size,
                              hipStream_t stream) {
    const float* tensor = (const float*)d_in[0];
    const float* rbf    = (const float*)d_in[1];
    const float* rij    = (const float*)d_in[2];
    const float* W1     = (const float*)d_in[3];
    const float* b1     = (const float*)d_in[4];
    const float* W2     = (const float*)d_in[5];
    const float* b2     = (const float*)d_in[6];
    float* out = (float*)d_out;

    hipMemsetAsync(out, 0, (size_t)out_size * sizeof(float), stream);
    dim3 grid(2 * N_ * 2), block(256);   // 2-way k-split
    filter_mfma2<<<grid, block, 0, stream>>>(tensor, rbf, rij, W1, b1, W2, b2, out);
}